// Round 12
// baseline (878.644 us; speedup 1.0000x reference)
//
#include <hip/hip_runtime.h>
#include <hip/hip_bf16.h>

using u16 = unsigned short;
using u32 = unsigned int;

typedef __attribute__((ext_vector_type(8))) short bf8;   // 8 x bf16 bits (4 VGPR)
typedef __attribute__((ext_vector_type(4))) float f4;    // MFMA acc
typedef __attribute__((ext_vector_type(4))) u16  us4;

#define DEV static __device__ __forceinline__

DEV float bf2f(u16 u) { return __uint_as_float(((u32)u) << 16); }
DEV u16 f2bf(float f) {
    u32 x = __float_as_uint(f);
    x += 0x7FFFu + ((x >> 16) & 1u);          // RNE
    return (u16)(x >> 16);
}
DEV float tanhf_fast(float x) {               // tanh = 1 - 2/(e^{2x}+1)
    float e = __expf(2.0f * x);
    return 1.0f - 2.0f / (e + 1.0f);
}
DEV f4 MFMA(bf8 a, bf8 b, f4 c) {
    return __builtin_amdgcn_mfma_f32_16x16x32_bf16(a, b, c, 0, 0, 0);
}
// XCD-aware bijective swizzle for grids with nwg.x % 8 == 0 (T1)
DEV int xcd_swz(int bx, int nwg) { return (bx & 7) * (nwg >> 3) + (bx >> 3); }
// Persistent mapping for 256-block grids: XCD(bx)=bx&7 (assumed); each XCD gets ONE
// col-group (grp = bx&1) and 32 row-panels -> B working set 2MB <= L2 per XCD.
DEV void persist_map(int bx, int& row, int& grp) {
    row = ((bx >> 3) << 2) | ((bx >> 1) & 3);   // 0..127, bijective with grp
    grp = bx & 1;
}

DEV void gload16(const u16* src, u16* dst) {
    __builtin_amdgcn_global_load_lds(
        (const __attribute__((address_space(1))) void*)src,
        (__attribute__((address_space(3))) void*)dst, 16, 0, 0);
}

#define SBAR()  __builtin_amdgcn_s_barrier()
#define SCHED() __builtin_amdgcn_sched_barrier(0)

// ---------------- constants ----------------
// D=1024 E=2048 S_DIM=128 C=256 SRC=4096 G=16 B=8, M = B*SRC = 32768 rows
// GEMM row order r = b*4096 + s; xb stored r-major [r][1024]

// ---------------- workspace layout (bytes) ----------------
#define WS_XB    ((size_t)0)                    // bf16 x, [r][1024]                      64 MiB
#define WS_WXST  ((size_t)67108864)             // WxsT [128][1024]                       256 KiB
#define WS_WVET  ((size_t)67371008)             // WveT [2048][1024]                      4 MiB
#define WS_WUET  ((size_t)71565312)             // WueT [2048][1024]                      4 MiB
#define WS_WODT  ((size_t)75759616)             // WodT [1024][2048]                      4 MiB
#define WS_KVT   ((size_t)79953920)             // kvT bf16 [B][2048][128]                4 MiB
#define WS_A     ((size_t)84148224)             // a bf16 [128][256][256]                 16 MiB
#define WS_QL    ((size_t)100925440)            // ql bf16 [32768][128] (live in k_t1)    8 MiB
#define WS_VT    ((size_t)109314048)            // vT bf16 [B][2048][4096]                128 MiB
#define WS_T1    ((size_t)243531776)            // t1/t2 bf16 [32768][2048]               128 MiB
// --- aliases inside the t1 block: all dead before k_t1 writes t1 ---
#define WS_Z     ((size_t)243531776)            // z bf16 [32768][128]   (dead after k_klinT)  8 MiB
#define WS_KLT   ((size_t)251920384)            // klinT bf16 [B][128][4096] (dead after k_kv) 8 MiB
#define WS_QQ    ((size_t)260308992)            // qq bf16 [32768][128]  (dead after k_a)      8 MiB
#define WS_KQ    ((size_t)268697600)            // kq bf16 [32768][128]  (dead after k_a)      8 MiB
#define WS_KVF   ((size_t)277086208)            // kvF f32 [B][2048][128] (dead after k_kvcvt) 8 MiB
// total 377,749,504 bytes

// ================= 128^2 staged-GEMM building blocks (for k_zgemm / k_kv) =================
DEV void stage128x64(const u16* __restrict__ gbase, int ld, u16* lds, int w, int lane) {
    const int srow = lane >> 3;                       // 0..7
    const int scol = ((lane & 7) ^ srow) * 8;         // pre-swizzled source slot
    #pragma unroll
    for (int i = 0; i < 4; i++) {
        const int rt = (i * 4 + w) * 8 + srow;
        gload16(gbase + (size_t)rt * ld + scol, lds + (size_t)(i * 4 + w) * 512);
    }
}

DEV void frag_mfma_64_swz(const u16* As, const u16* Bs, int wm, int wn, int ln, int lh,
                          f4 acc[4][4]) {
    #pragma unroll
    for (int kk2 = 0; kk2 < 2; kk2++) {
        const int sx = (((kk2 << 2) + lh) ^ (ln & 7)) << 3;   // swizzled slot offset (elems)
        bf8 a[4], b[4];
        #pragma unroll
        for (int mt = 0; mt < 4; mt++)
            a[mt] = *reinterpret_cast<const bf8*>(As + (wm * 64 + mt * 16 + ln) * 64 + sx);
        #pragma unroll
        for (int nt = 0; nt < 4; nt++)
            b[nt] = *reinterpret_cast<const bf8*>(Bs + (wn * 64 + nt * 16 + ln) * 64 + sx);
        #pragma unroll
        for (int mt = 0; mt < 4; mt++)
            #pragma unroll
            for (int nt = 0; nt < 4; nt++)
                acc[mt][nt] = MFMA(a[mt], b[nt], acc[mt][nt]);
    }
}

template<int NT, typename FA, typename FB>
DEV void gemm_pipe(FA stageA, FB stageB, u16* As, u16* Bs,
                   int wm, int wn, int ln, int lh, f4 acc[4][4]) {
    stageA(As, 0); stageB(Bs, 0);                    // 8 loads in flight
    #pragma unroll 2
    for (int t = 0; t + 1 < NT; ++t) {
        u16* An = As + ((t & 1) ^ 1) * 8192;
        u16* Bn = Bs + ((t & 1) ^ 1) * 8192;
        stageA(An, t + 1); stageB(Bn, t + 1);        // 16 in flight
        asm volatile("s_waitcnt vmcnt(8)" ::: "memory");   // oldest 8 (current tile) done
        SBAR(); SCHED();
        frag_mfma_64_swz(As + (t & 1) * 8192, Bs + (t & 1) * 8192, wm, wn, ln, lh, acc);
        SCHED(); SBAR(); SCHED();
    }
    asm volatile("s_waitcnt vmcnt(0)" ::: "memory");
    SBAR();
    frag_mfma_64_swz(As + ((NT - 1) & 1) * 8192, Bs + ((NT - 1) & 1) * 8192, wm, wn, ln, lh, acc);
    SBAR();
}

// ================= 256^2 8-phase pipeline, deep prefetch, persistent panels ================
// LDS: 2 dbuf x (A[256][64] + B[256][64]) = 128 KiB. Wave (wm = w>>2 in {0,1}, wn = w&3).
// Per K-tile t: 4 phases = C-quadrants. ALL of tile t+2 staged at P3/P4 into buffer cur.
// vmcnt(8) at P4 completes tile t+1. Never 0 in steady state. Tiles map across multiple
// output col-panels (persistent block); epi(p) dumps+zeros acc at panel boundaries
// ((t & PMASK)==PMASK) while the prefetch pipeline continues uninterrupted.

#define T256 16384   // elements per 256x64 tile

// stage 2 of the 4 row-quarter loads of a 256x64 tile (i0, i1 in 0..3; 64 rows each)
DEV void stage2(const u16* __restrict__ gbase, int ld, u16* lds, int tid, int i0, int i1) {
    const int slot = tid & 7;
    {
        const int row = i0 * 64 + (tid >> 3);
        gload16(gbase + (size_t)row * ld + ((slot ^ (row & 7)) << 3),
                lds + ((size_t)(i0 * 512 + (tid & ~63)) << 3));
    }
    {
        const int row = i1 * 64 + (tid >> 3);
        gload16(gbase + (size_t)row * ld + ((slot ^ (row & 7)) << 3),
                lds + ((size_t)(i1 * 512 + (tid & ~63)) << 3));
    }
}

DEV const bf8* frag_ptr(const u16* base, int row, int ks, int lh) {
    const int slot = ((ks << 2) + lh) ^ (row & 7);
    return reinterpret_cast<const bf8*>(base + row * 64 + slot * 8);
}

template<int NT, int PSHIFT, typename FA, typename FB, typename FE>
DEV void gemm_pipe8(FA sA, FB sB, FE epi, u16* As, u16* Bs,
                    int wm, int wn, int ln, int lh, f4 acc[8][4]) {
    constexpr int PMASK = (1 << PSHIFT) - 1;
    // prologue: stage tile0 AND tile1 fully (16 loads); vmcnt(8) -> tile0 resident
    sA(As, 0, 0, 2); sA(As, 0, 1, 3); sB(Bs, 0, 0, 1); sB(Bs, 0, 2, 3);
    if (NT > 1) {
        sA(As + T256, 1, 0, 2); sA(As + T256, 1, 1, 3);
        sB(Bs + T256, 1, 0, 1); sB(Bs + T256, 1, 2, 3);
        asm volatile("s_waitcnt vmcnt(8)" ::: "memory");
    } else {
        asm volatile("s_waitcnt vmcnt(0)" ::: "memory");
    }
    SBAR(); SCHED();
    auto body = [&](int t, const int c) {
        const u16* Ab = As + c * T256;
        const u16* Bb = Bs + c * T256;
        u16* Ac = As + c * T256;       // stage target for tile t+2 (same parity)
        u16* Bc = Bs + c * T256;
        bf8 aR[8], b0[4], b1[4];
        // ---- P1 (mg0, ng0): read aR(mg0) + b0; no staging ----
        #pragma unroll
        for (int j = 0; j < 4; j++) {
            aR[j]     = *frag_ptr(Ab, wm * 128 + j * 16 + ln, 0, lh);
            aR[4 + j] = *frag_ptr(Ab, wm * 128 + j * 16 + ln, 1, lh);
        }
        #pragma unroll
        for (int k = 0; k < 2; k++) {
            b0[k]     = *frag_ptr(Bb, wn * 64 + k * 16 + ln, 0, lh);
            b0[2 + k] = *frag_ptr(Bb, wn * 64 + k * 16 + ln, 1, lh);
        }
        SBAR(); SCHED();
        __builtin_amdgcn_s_setprio(1);
        #pragma unroll
        for (int j = 0; j < 4; j++) { acc[j][0] = MFMA(aR[j], b0[0], acc[j][0]);
                                      acc[j][1] = MFMA(aR[j], b0[1], acc[j][1]); }
        #pragma unroll
        for (int j = 0; j < 4; j++) { acc[j][0] = MFMA(aR[4 + j], b0[2], acc[j][0]);
                                      acc[j][1] = MFMA(aR[4 + j], b0[3], acc[j][1]); }
        __builtin_amdgcn_s_setprio(0);
        SCHED();
        // ---- P2 (mg0, ng1): read b1; no staging ----
        #pragma unroll
        for (int k = 0; k < 2; k++) {
            b1[k]     = *frag_ptr(Bb, wn * 64 + (2 + k) * 16 + ln, 0, lh);
            b1[2 + k] = *frag_ptr(Bb, wn * 64 + (2 + k) * 16 + ln, 1, lh);
        }
        SBAR(); SCHED();
        __builtin_amdgcn_s_setprio(1);
        #pragma unroll
        for (int j = 0; j < 4; j++) { acc[j][2] = MFMA(aR[j], b1[0], acc[j][2]);
                                      acc[j][3] = MFMA(aR[j], b1[1], acc[j][3]); }
        #pragma unroll
        for (int j = 0; j < 4; j++) { acc[j][2] = MFMA(aR[4 + j], b1[2], acc[j][2]);
                                      acc[j][3] = MFMA(aR[4 + j], b1[3], acc[j][3]); }
        __builtin_amdgcn_s_setprio(0);
        SCHED();
        // ---- P3 (mg1, ng0): read aR(mg1); stage A(t+2){0,2} + B(t+2)h0 ----
        #pragma unroll
        for (int j = 0; j < 4; j++) {
            aR[j]     = *frag_ptr(Ab, wm * 128 + 64 + j * 16 + ln, 0, lh);
            aR[4 + j] = *frag_ptr(Ab, wm * 128 + 64 + j * 16 + ln, 1, lh);
        }
        if (t + 2 < NT) { sA(Ac, t + 2, 0, 2); sB(Bc, t + 2, 0, 1); }
        SBAR(); SCHED();
        __builtin_amdgcn_s_setprio(1);
        #pragma unroll
        for (int j = 0; j < 4; j++) { acc[4 + j][0] = MFMA(aR[j], b0[0], acc[4 + j][0]);
                                      acc[4 + j][1] = MFMA(aR[j], b0[1], acc[4 + j][1]); }
        #pragma unroll
        for (int j = 0; j < 4; j++) { acc[4 + j][0] = MFMA(aR[4 + j], b0[2], acc[4 + j][0]);
                                      acc[4 + j][1] = MFMA(aR[4 + j], b0[3], acc[4 + j][1]); }
        __builtin_amdgcn_s_setprio(0);
        SCHED();
        // ---- P4 (mg1, ng1): stage A(t+2){1,3} + B(t+2)h1; counted vmcnt; no ds_reads ----
        if (t + 2 < NT) {
            sA(Ac, t + 2, 1, 3); sB(Bc, t + 2, 2, 3);
            asm volatile("s_waitcnt vmcnt(8)" ::: "memory");   // tile t+1 resident; t+2 floats
        } else if (t + 1 < NT) {
            asm volatile("s_waitcnt vmcnt(0)" ::: "memory");   // tail drain
        }
        SBAR(); SCHED();
        __builtin_amdgcn_s_setprio(1);
        #pragma unroll
        for (int j = 0; j < 4; j++) { acc[4 + j][2] = MFMA(aR[j], b1[0], acc[4 + j][2]);
                                      acc[4 + j][3] = MFMA(aR[j], b1[1], acc[4 + j][3]); }
        #pragma unroll
        for (int j = 0; j < 4; j++) { acc[4 + j][2] = MFMA(aR[4 + j], b1[2], acc[4 + j][2]);
                                      acc[4 + j][3] = MFMA(aR[4 + j], b1[3], acc[4 + j][3]); }
        __builtin_amdgcn_s_setprio(0);
        SCHED();
    };
    for (int t = 0; t < NT; t += 2) {   // NT even for all call sites
        body(t, 0);
        if ((t & PMASK) == PMASK) epi(t >> PSHIFT);
        body(t + 1, 1);
        if (((t + 1) & PMASK) == PMASK) epi((t + 1) >> PSHIFT);
    }
}

// ---------------- conversion kernels ----------------
// value [s][b][d] f32 -> xb [b*4096+s][d] bf16
__global__ void k_cvt_x(const float* __restrict__ src, u16* __restrict__ dst) {
    int m = blockIdx.x;                 // m = s*8 + b
    int s = m >> 3, b = m & 7;
    const float* in = src + (size_t)m * 1024;
    u16* outp = dst + (((size_t)b << 12) + s) * 1024;
    int t = threadIdx.x * 4;
    float4 v = *reinterpret_cast<const float4*>(in + t);
    us4 o; o[0] = f2bf(v.x); o[1] = f2bf(v.y); o[2] = f2bf(v.z); o[3] = f2bf(v.w);
    *reinterpret_cast<us4*>(outp + t) = o;
}

// src[R][C] f32 -> dst[C][R] bf16
__global__ void k_transpose(const float* __restrict__ src, u16* __restrict__ dst, int R, int C) {
    __shared__ u16 tile[32][33];
    int tx = threadIdx.x & 31, ty = threadIdx.x >> 5;   // 256 thr: 32x8
    int r0 = blockIdx.y * 32, c0 = blockIdx.x * 32;
    #pragma unroll
    for (int rr = ty; rr < 32; rr += 8)
        tile[rr][tx] = f2bf(src[(size_t)(r0 + rr) * C + c0 + tx]);
    __syncthreads();
    #pragma unroll
    for (int cc = ty; cc < 32; cc += 8)
        dst[(size_t)(c0 + cc) * R + r0 + tx] = tile[tx][cc];
}

// z rows -> klinT[b][s][pos] with affine (gamma3,beta3)
__global__ void k_klinT(const u16* __restrict__ z, const float* __restrict__ gamma,
                        const float* __restrict__ beta, u16* __restrict__ klt) {
    __shared__ u16 tile[32][33];
    int tx = threadIdx.x & 31, ty = threadIdx.x >> 5;
    int r0 = blockIdx.x * 32;            // global row (0..32767)
    int c0 = blockIdx.y * 32;            // s col (0..127)
    float gs = gamma[384 + c0 + tx], bs = beta[384 + c0 + tx];
    #pragma unroll
    for (int rr = ty; rr < 32; rr += 8) {
        u16 zv = z[(size_t)(r0 + rr) * 128 + c0 + tx];
        tile[rr][tx] = f2bf(bf2f(zv) * gs + bs);
    }
    __syncthreads();
    int b = r0 >> 12;
    int pos0 = r0 & 4095;
    #pragma unroll
    for (int cc = ty; cc < 32; cc += 8)
        klt[(((size_t)b * 128 + c0 + cc) << 12) + pos0 + tx] = tile[tx][cc];
}

// ---------------- z/qq/kq/ql = affine(tanh(x @ Wxs + bxs)) (pipelined 128^2) ----------------
__global__ __launch_bounds__(256) void k_zgemm(const u16* __restrict__ xb, const u16* __restrict__ WxsT,
                                               const float* __restrict__ bxs,
                                               const float* __restrict__ gamma, const float* __restrict__ beta,
                                               u16* __restrict__ z, u16* __restrict__ qq,
                                               u16* __restrict__ kq, u16* __restrict__ ql) {
    __shared__ u16 As[2][128 * 64];
    __shared__ u16 Bs[2][128 * 64];
    const int tid = threadIdx.x;
    const int lane = tid & 63, w = tid >> 6;
    const int ln = lane & 15, lh = lane >> 4;
    const int wm = w >> 1, wn = w & 1;
    const int rowbase = xcd_swz(blockIdx.x, 256) * 128;
    const u16* Ab = xb + (size_t)rowbase * 1024;
    f4 acc[4][4] = {};
    gemm_pipe<16>(
        [&](u16* l, int t) { stage128x64(Ab + t * 64, 1024, l, w, lane); },
        [&](u16* l, int t) { stage128x64(WxsT + t * 64, 1024, l, w, lane); },
        As[0], Bs[0], wm, wn, ln, lh, acc);
    #pragma unroll
    for (int mt = 0; mt < 4; mt++)
        #pragma unroll
        for (int nt = 0; nt < 4; nt++) {
            int col = wn * 64 + nt * 16 + ln;
            float bias = bxs[col];
            float g0 = gamma[col],       b0 = beta[col];
            float g1 = gamma[128 + col], b1 = beta[128 + col];
            float g2 = gamma[256 + col], b2 = beta[256 + col];
            int r0 = rowbase + wm * 64 + mt * 16 + lh * 4;
            #pragma unroll
            for (int rg = 0; rg < 4; rg++) {
                float zv = tanhf_fast(acc[mt][nt][rg] + bias);
                size_t idx = ((size_t)(r0 + rg) << 7) + col;
                z[idx]  = f2bf(zv);
                qq[idx] = f2bf(zv * g0 + b0);
                kq[idx] = f2bf(zv * g1 + b1);
                ql[idx] = f2bf(zv * g2 + b2);
            }
        }
}

// -------- vT = tanh(x @ Wve + bve)^T : bf16 [B][2048][4096] (256^2, persistent 4 panels) --------
__global__ __launch_bounds__(512, 2) void k_vgemm(const u16* __restrict__ xb, const u16* __restrict__ WveT,
                                                  const float* __restrict__ bve, u16* __restrict__ vT) {
    __shared__ u16 As[2 * T256];
    __shared__ u16 Bs[2 * T256];
    const int tid = threadIdx.x;
    const int lane = tid & 63, w = tid >> 6;
    const int ln = lane & 15, lh = lane >> 4;
    const int wm = w >> 2, wn = w & 3;
    int rowt, grp;
    persist_map(blockIdx.x, rowt, grp);              // 128 rows x 2 groups (of 4 col-panels)
    const int rowbase = rowt * 256;
    const int grpcol = grp * 1024;
    const u16* Ag = xb + (size_t)rowbase * 1024;
    const u16* Bg = WveT + (size_t)grpcol * 1024;
    f4 acc[8][4] = {};
    gemm_pipe8<64, 4>(
        [&](u16* l, int T, int i0, int i1) { stage2(Ag + (T & 15) * 64, 1024, l, tid, i0, i1); },
        [&](u16* l, int T, int i0, int i1) {
            stage2(Bg + (((size_t)(T >> 4)) << 18) + (T & 15) * 64, 1024, l, tid, i0, i1); },
        [&](int p) {
            const int colbase = grpcol + p * 256;
            #pragma unroll
            for (int mt = 0; mt < 8; mt++)
                #pragma unroll
                for (int nt = 0; nt < 4; nt++) {
                    int e = colbase + wn * 64 + nt * 16 + ln;
                    float bias = bve[e];
                    int r0 = rowbase + wm * 128 + mt * 16 + lh * 4;
                    int bb = r0 >> 12, s0 = r0 & 4095;
                    us4 pk;
                    #pragma unroll
                    for (int rg = 0; rg < 4; rg++) {
                        pk[rg] = f2bf(tanhf_fast(acc[mt][nt][rg] + bias));
                        acc[mt][nt][rg] = 0.0f;
                    }
                    *reinterpret_cast<us4*>(vT + (((size_t)bb * 2048 + e) << 12) + s0) = pk;
                }
        },
        As, Bs, wm, wn, ln, lh, acc);
}

// ---------------- kvF[b][e][s] += vT[b][e][kseg] @ klinT[b][s][kseg] (pipelined 128^2, K-split x4) --------
__global__ __launch_bounds__(256) void k_kv(const u16* __restrict__ vT, const u16* __restrict__ klt,
                                            float* __restrict__ kvF) {
    __shared__ u16 As[2][128 * 64];
    __shared__ u16 Bs[2][128 * 64];
    const int tid = threadIdx.x;
    const int lane = tid & 63, w = tid >> 6;
    const int ln = lane & 15, lh = lane >> 4;
    const int wm = w >> 1, wn = w & 1;
    const int b = blockIdx.z;
    const int rowbase = blockIdx.x * 128;            // e
    const int kbase = blockIdx.y * 1024;             // pos segment
    const u16* Ab = vT + ((size_t)b * 2048 + rowbase) * 4096 + kbase;
    const u16* Bb = klt + ((size_t)b * 128) * 4096 + kbase;
    f4 acc[4][4] = {};
    gemm_pipe<16>(
        [&](u16* l, int t) { stage128x64(Ab + t * 64, 4096, l, w, lane); },
        [&](u16* l, int t) { stage128x64(Bb + t * 64, 4096, l, w, lane); },
        As[0], Bs[0], wm, wn, ln, lh, acc);
    #pragma unroll
    for (int mt = 0; mt < 4; mt++)
        #pragma unroll
        for (int nt = 0; nt < 4; nt++) {
            int s = wn * 64 + nt * 16 + ln;
            int e0 = rowbase + wm * 64 + mt * 16 + lh * 4;
            #pragma unroll
            for (int rg = 0; rg < 4; rg++)
                atomicAdd(&kvF[(((size_t)b * 2048 + e0 + rg) << 7) + s], acc[mt][nt][rg]);
        }
}

__global__ void k_kvcvt(const float* __restrict__ kvF, u16* __restrict__ kvT, int n) {
    int i = (blockIdx.x * blockDim.x + threadIdx.x) * 4;
    if (i < n) {
        float4 v = *reinterpret_cast<const float4*>(kvF + i);
        us4 o; o[0] = f2bf(v.x); o[1] = f2bf(v.y); o[2] = f2bf(v.z); o[3] = f2bf(v.w);
        *reinterpret_cast<us4*>(kvT + i) = o;
    }
}

// ---------------- a = relu(qq @ kq^T + rel_bias)^2 : bf16 [128][256][256] (pure GEMM) ----------------
__global__ __launch_bounds__(256) void k_a(const u16* __restrict__ qq, const u16* __restrict__ kq,
                                           const float* __restrict__ rel_bias, u16* __restrict__ a_out) {
    const int lane = threadIdx.x & 63, wid = threadIdx.x >> 6;
    const int ln = lane & 15, lh = lane >> 4;
    const int wm = wid >> 1, wn = wid & 1;
    const int ci = blockIdx.y;
    const int qbase = blockIdx.x * 128 + wm * 64;    // q rows within chunk
    const int nbase = wn * 128;                      // key cols within chunk
    const int rowbase = ci << 8;
    f4 acc[4][8] = {};
    const u16* qr[4];
    #pragma unroll
    for (int mt = 0; mt < 4; mt++) qr[mt] = qq + ((size_t)(rowbase + qbase + mt * 16 + ln) << 7);
    const u16* kr[8];
    #pragma unroll
    for (int nt = 0; nt < 8; nt++) kr[nt] = kq + ((size_t)(rowbase + nbase + nt * 16 + ln) << 7);
    #pragma unroll
    for (int kk = 0; kk < 128; kk += 32) {
        int k0 = kk + lh * 8;
        bf8 aq[4], ak[8];
        #pragma unroll
        for (int mt = 0; mt < 4; mt++) aq[mt] = *reinterpret_cast<const bf8*>(qr[mt] + k0);
        #pragma unroll
        for (int nt = 0; nt < 8; nt++) ak[nt] = *reinterpret_cast<const bf8*>(kr[nt] + k0);
        #pragma unroll
        for (int mt = 0; mt < 4; mt++)
            #pragma unroll
            for (int nt = 0; nt < 8; nt++)
                acc[mt][nt] = MFMA(aq[mt], ak[nt], acc[mt][nt]);
    }
    #pragma unroll
    for (int nt = 0; nt < 8; nt++) {
        int key = nbase + nt * 16 + ln;
        float rb = rel_bias[key];
        #pragma unroll
        for (int mt = 0; mt < 4; mt++) {
            int r0 = qbase + mt * 16 + lh * 4;
            #pragma unroll
            for (int rg = 0; rg < 4; rg++) {
                float v = acc[mt][nt][rg] + rb;
                v = fmaxf(v, 0.0f); v = v * v;
                a_out[((size_t)ci << 16) + ((size_t)(r0 + rg) << 8) + key] = f2bf(v);
            }
        }
    }
}

// ---------------- t2 = ql @ kv + a @ v : bf16 [32768][2048] (256^2, 6-tile 8-phase deep) --------
__global__ __launch_bounds__(512, 2) void k_t1(const u16* __restrict__ ql, const u16* __restrict__ a_in,
                                               const u16* __restrict__ vT, const u16* __restrict__ kvT,
                                               u16* __restrict__ t1) {
    __shared__ u16 As[2 * T256];
    __shared__ u16 Bs[2 * T256];
    const int tid = threadIdx.x;
    const int lane = tid & 63, w = tid >> 6;
    const int ln = lane & 15, lh = lane >> 4;
    const int wm = w >> 2, wn = w & 3;
    const int ci = xcd_swz(blockIdx.x, 128);         // chunk == 256-row block
    const int rowbase = ci << 8;
    const int ebase = blockIdx.y * 256;
    const int b = ci >> 4, g = ci & 15;
    const u16* Aa = ql + (size_t)rowbase * 128;                       // tiles 0-1 (ld 128)
    const u16* Ba = kvT + ((size_t)(b * 2048 + ebase)) * 128;         // tiles 0-1 (ld 128)
    const u16* Ab2 = a_in + ((size_t)ci << 16);                       // tiles 2-5 (ld 256)
    const u16* Bb2 = vT + ((size_t)(b * 2048 + ebase)) * 4096 + (g << 8);  // tiles 2-5 (ld 4096)
    f4 acc[8][4] = {};
    gemm_pipe8<6, 10>(
        [&](u16* l, int t, int i0, int i1) {
            if (t < 2) stage2(Aa + t * 64, 128, l, tid, i0, i1);
            else       stage2(Ab2 + (t - 2) * 64, 256, l, tid, i0, i1);
        },
        [&](u16* l, int t, int i0, int i1) {
            if (t < 2) stage2(Ba + t * 64, 128, l, tid, i0, i1);
            else       stage2(Bb2 + (t - 2) * 64, 4096, l, tid, i0, i1);
        },
        [&](int) {},
        As, Bs, wm, wn, ln, lh, acc);
    #pragma unroll
    for (int mt = 0; mt < 8; mt++)
        #pragma unroll
        for (int nt = 0; nt < 4; nt++) {
            int e = ebase + wn * 64 + nt * 16 + ln;
            int r0 = rowbase + wm * 128 + mt * 16 + lh * 4;
            #pragma unroll
            for (int rg = 0; rg < 4; rg++)
                t1[((size_t)(r0 + rg) << 11) + e] = f2bf(acc[mt][nt][rg]);
        }
}

// -------- t1 = tanh(x @ Wue + bue) * t2 (in place, 256^2, persistent 4 panels) --------
__global__ __launch_bounds__(512, 2) void k_u(const u16* __restrict__ xb, const u16* __restrict__ WueT,
                                              const float* __restrict__ bue, u16* t1) {
    __shared__ u16 As[2 * T256];
    __shared__ u16 Bs[2 * T256];
    const int tid = threadIdx.x;
    const int lane = tid & 63, w = tid >> 6;
    const int ln = lane & 15, lh = lane >> 4;
    const int wm = w >> 2, wn = w & 3;
    int rowt, grp;
    persist_map(blockIdx.x, rowt, grp);              // 128 rows x 2 groups (of 4 col-panels)
    const int rowbase = rowt * 256;
    const int grpcol = grp * 1024;
    const u16* Ag = xb + (size_t)rowbase * 1024;
    const u16* Bg = WueT + (size_t)grpcol * 1024;
    f4 acc[8][4] = {};
    gemm_pipe8<64, 4>(
        [&](u16* l, int T, int i0, int i1) { stage2(Ag + (T & 15) * 64, 1024, l, tid, i0, i1); },
        [&](u16* l, int T, int i0, int i1) {
            stage2(Bg + (((size_t)(T >> 4)) << 18) + (T & 15) * 64, 1024, l, tid, i0, i1); },
        [&](int p) {
            const int colbase = grpcol + p * 256;
            #pragma unroll
            for (int mt = 0; mt < 8; mt++)
                #pragma unroll
                for (int nt = 0; nt < 4; nt++) {
                    int e = colbase + wn * 64 + nt * 16 + ln;
                    float bias = bue[e];
                    int r0 = rowbase + wm * 128 + mt * 16 + lh * 4;
                    #pragma unroll
                    for (int rg = 0; rg < 4; rg++) {
                        size_t idx = ((size_t)(r0 + rg) << 11) + e;
                        float t = bf2f(t1[idx]);
                        float u = tanhf_fast(acc[mt][nt][rg] + bias);
                        t1[idx] = f2bf(u * t);
                        acc[mt][nt][rg] = 0.0f;
                    }
                }
        },
        As, Bs, wm, wn, ln, lh, acc);
}

// -------- out = t1 @ Wod + bod -> [s][b][d] f32 (256^2, persistent 2 panels) --------
__global__ __launch_bounds__(512, 2) void k_o(const u16* __restrict__ t1, const u16* __restrict__ WodT,
                                              const float* __restrict__ bod, float* __restrict__ out) {
    __shared__ u16 As[2 * T256];
    __shared__ u16 Bs[2 * T256];
    const int tid = threadIdx.x;
    const int lane = tid & 63, w = tid >> 6;
    const int ln = lane & 15, lh = lane >> 4;
    const int wm = w >> 2, wn = w & 3;
    int rowt, grp;
    persist_map(blockIdx.x, rowt, grp);              // 128 rows x 2 groups (of 2 col-panels)
    const int rowbase = rowt * 256;
    const int grpcol = grp * 512;
    const u16* Ag = t1 + (size_t)rowbase * 2048;
    const u16* Bg = WodT + (size_t)grpcol * 2048;
    f4 acc[8][4] = {};
    gemm_pipe8<64, 5>(
        [&](u16* l, int T, int i0, int i1) { stage2(Ag + (T & 31) * 64, 2048, l, tid, i0, i1); },
        [&](u16* l, int T, int i0, int i1) {
            stage2(Bg + (size_t)(T >> 5) * 524288 + (T & 31) * 64, 2048, l, tid, i0, i1); },
        [&](int p) {
            const int colbase = grpcol + p * 256;
            #pragma unroll
            for (int mt = 0; mt < 8; mt++)
                #pragma unroll
                for (int nt = 0; nt < 4; nt++) {
                    int d = colbase + wn * 64 + nt * 16 + ln;
                    float bias = bod[d];
                    int r0 = rowbase + wm * 128 + mt * 16 + lh * 4;
                    #pragma unroll
                    for (int rg = 0; rg < 4; rg++) {
                        int r = r0 + rg;
                        int s = r & 4095, bb = r >> 12;
                        out[((size_t)(s * 8 + bb) << 10) + d] = acc[mt][nt][rg] + bias;
                        acc[mt][nt][rg] = 0.0f;
                    }
                }
        },
        As, Bs, wm, wn, ln, lh, acc);
}

extern "C" void kernel_launch(void* const* d_in, const int* in_sizes, int n_in,
                              void* d_out, int out_size, void* d_ws, size_t ws_size,
                              hipStream_t stream) {
    const float* value = (const float*)d_in[2];
    const float* Wxs = (const float*)d_in[3];  const float* bxs = (const float*)d_in[4];
    const float* Wve = (const float*)d_in[5];  const float* bve = (const float*)d_in[6];
    const float* Wue = (const float*)d_in[7];  const float* bue = (const float*)d_in[8];
    const float* Wod = (const float*)d_in[9];  const float* bod = (const float*)d_in[10];
    const float* rel_bias = (const float*)d_in[11];
    const float* gamma = (const float*)d_in[12];
    const float* beta  = (const float*)d_in[13];
    float* out = (float*)d_out;

    char* ws = (char*)d_ws;
    u16* xb   = (u16*)(ws + WS_XB);
    u16* WxsT = (u16*)(ws + WS_WXST);
    u16* WveT = (u16*)(ws + WS_WVET);
    u16* WueT = (u16*)(ws + WS_WUET);
    u16* WodT = (u16*)(ws + WS_WODT);
    u16* kvT  = (u16*)(ws + WS_KVT);
    u16* a    = (u16*)(ws + WS_A);
    u16* ql   = (u16*)(ws + WS_QL);
    u16* vT   = (u16*)(ws + WS_VT);
    u16* t1   = (u16*)(ws + WS_T1);
    u16* z    = (u16*)(ws + WS_Z);
    u16* klt  = (u16*)(ws + WS_KLT);
    u16* qq   = (u16*)(ws + WS_QQ);
    u16* kq   = (u16*)(ws + WS_KQ);
    float* kvF = (float*)(ws + WS_KVF);

    // conversions
    k_cvt_x<<<32768, 256, 0, stream>>>(value, xb);
    k_transpose<<<dim3(4, 32),  256, 0, stream>>>(Wxs, WxsT, 1024, 128);
    k_transpose<<<dim3(64, 32), 256, 0, stream>>>(Wve, WveT, 1024, 2048);
    k_transpose<<<dim3(64, 32), 256, 0, stream>>>(Wue, WueT, 1024, 2048);
    k_transpose<<<dim3(32, 64), 256, 0, stream>>>(Wod, WodT, 2048, 1024);
    // z + affine variants (pipelined 128^2)
    k_zgemm<<<256, 256, 0, stream>>>(xb, WxsT, bxs, gamma, beta, z, qq, kq, ql);
    // k_lin transposed
    k_klinT<<<dim3(1024, 4), 256, 0, stream>>>(z, gamma, beta, klt);
    // v (256^2, persistent 4 panels/block)
    k_vgemm<<<256, 512, 0, stream>>>(xb, WveT, bve, vT);
    // kv (pipelined 128^2, K-split x4 atomics)
    hipMemsetAsync(kvF, 0, (size_t)8 * 2048 * 128 * 4, stream);
    k_kv<<<dim3(16, 4, 8), 256, 0, stream>>>(vT, klt, kvF);
    k_kvcvt<<<2048, 256, 0, stream>>>(kvF, kvT, 8 * 2048 * 128);
    // quadratic attention scores (pure GEMM)
    k_a<<<dim3(2, 128), 256, 0, stream>>>(qq, kq, rel_bias, a);
    // t2 = v_quad + v_lin (256^2, 6 tiles, 8-phase deep)
    k_t1<<<dim3(128, 8), 512, 0, stream>>>(ql, a, vT, kvT, t1);
    // t1 = tanh(u) * t2 (256^2, persistent 4 panels/block, in place)
    k_u<<<256, 512, 0, stream>>>(xb, WueT, bue, t1);
    // out (256^2, persistent 2 panels/block)
    k_o<<<256, 512, 0, stream>>>(t1, WodT, bod, out);
}

// Round 13
// 731.026 us; speedup vs baseline: 1.2019x; 1.2019x over previous
//
#include <hip/hip_runtime.h>
#include <hip/hip_bf16.h>

using u16 = unsigned short;
using u32 = unsigned int;

typedef __attribute__((ext_vector_type(8))) short bf8;   // 8 x bf16 bits (4 VGPR)
typedef __attribute__((ext_vector_type(4))) float f4;    // MFMA acc
typedef __attribute__((ext_vector_type(4))) u16  us4;

#define DEV static __device__ __forceinline__

DEV float bf2f(u16 u) { return __uint_as_float(((u32)u) << 16); }
DEV u16 f2bf(float f) {
    u32 x = __float_as_uint(f);
    x += 0x7FFFu + ((x >> 16) & 1u);          // RNE
    return (u16)(x >> 16);
}
DEV float tanhf_fast(float x) {               // tanh = 1 - 2/(e^{2x}+1)
    float e = __expf(2.0f * x);
    return 1.0f - 2.0f / (e + 1.0f);
}
DEV f4 MFMA(bf8 a, bf8 b, f4 c) {
    return __builtin_amdgcn_mfma_f32_16x16x32_bf16(a, b, c, 0, 0, 0);
}
// XCD-aware bijective swizzle for grids with nwg.x % 8 == 0 (T1)
DEV int xcd_swz(int bx, int nwg) { return (bx & 7) * (nwg >> 3) + (bx >> 3); }

DEV void gload16(const u16* src, u16* dst) {
    __builtin_amdgcn_global_load_lds(
        (const __attribute__((address_space(1))) void*)src,
        (__attribute__((address_space(3))) void*)dst, 16, 0, 0);
}

#define SBAR()  __builtin_amdgcn_s_barrier()
#define SCHED() __builtin_amdgcn_sched_barrier(0)

// ---------------- constants ----------------
// D=1024 E=2048 S_DIM=128 C=256 SRC=4096 G=16 B=8, M = B*SRC = 32768 rows
// GEMM row order r = b*4096 + s; xb stored r-major [r][1024]

// ---------------- workspace layout (bytes) ----------------
#define WS_XB    ((size_t)0)                    // bf16 x, [r][1024]                      64 MiB
#define WS_WXST  ((size_t)67108864)             // WxsT [128][1024]                       256 KiB
#define WS_WVET  ((size_t)67371008)             // WveT [2048][1024]                      4 MiB
#define WS_WUET  ((size_t)71565312)             // WueT [2048][1024]                      4 MiB
#define WS_WODT  ((size_t)75759616)             // WodT [1024][2048]                      4 MiB
#define WS_KVT   ((size_t)79953920)             // kvT bf16 [B][2048][128]                4 MiB
#define WS_A     ((size_t)84148224)             // a bf16 [128][256][256]                 16 MiB
#define WS_QL    ((size_t)100925440)            // ql bf16 [32768][128] (live in k_t1)    8 MiB
#define WS_VT    ((size_t)109314048)            // vT bf16 [B][2048][4096]                128 MiB
#define WS_T1    ((size_t)243531776)            // t1/t2 bf16 [32768][2048]               128 MiB
// --- aliases inside the t1 block: all dead before k_t1 writes t1 ---
#define WS_Z     ((size_t)243531776)            // z bf16 [32768][128]   (dead after k_klinT)  8 MiB
#define WS_KLT   ((size_t)251920384)            // klinT bf16 [B][128][4096] (dead after k_kv) 8 MiB
#define WS_QQ    ((size_t)260308992)            // qq bf16 [32768][128]  (dead after k_a)      8 MiB
#define WS_KQ    ((size_t)268697600)            // kq bf16 [32768][128]  (dead after k_a)      8 MiB
#define WS_KVF   ((size_t)277086208)            // kvF f32 [B][2048][128] (dead after k_kvcvt) 8 MiB
// total 377,749,504 bytes

// ================= 128^2 staged-GEMM building blocks (for k_zgemm / k_kv) =================
DEV void stage128x64(const u16* __restrict__ gbase, int ld, u16* lds, int w, int lane) {
    const int srow = lane >> 3;                       // 0..7
    const int scol = ((lane & 7) ^ srow) * 8;         // pre-swizzled source slot
    #pragma unroll
    for (int i = 0; i < 4; i++) {
        const int rt = (i * 4 + w) * 8 + srow;
        gload16(gbase + (size_t)rt * ld + scol, lds + (size_t)(i * 4 + w) * 512);
    }
}

DEV void frag_mfma_64_swz(const u16* As, const u16* Bs, int wm, int wn, int ln, int lh,
                          f4 acc[4][4]) {
    #pragma unroll
    for (int kk2 = 0; kk2 < 2; kk2++) {
        const int sx = (((kk2 << 2) + lh) ^ (ln & 7)) << 3;   // swizzled slot offset (elems)
        bf8 a[4], b[4];
        #pragma unroll
        for (int mt = 0; mt < 4; mt++)
            a[mt] = *reinterpret_cast<const bf8*>(As + (wm * 64 + mt * 16 + ln) * 64 + sx);
        #pragma unroll
        for (int nt = 0; nt < 4; nt++)
            b[nt] = *reinterpret_cast<const bf8*>(Bs + (wn * 64 + nt * 16 + ln) * 64 + sx);
        #pragma unroll
        for (int mt = 0; mt < 4; mt++)
            #pragma unroll
            for (int nt = 0; nt < 4; nt++)
                acc[mt][nt] = MFMA(a[mt], b[nt], acc[mt][nt]);
    }
}

template<int NT, typename FA, typename FB>
DEV void gemm_pipe(FA stageA, FB stageB, u16* As, u16* Bs,
                   int wm, int wn, int ln, int lh, f4 acc[4][4]) {
    stageA(As, 0); stageB(Bs, 0);                    // 8 loads in flight
    #pragma unroll 2
    for (int t = 0; t + 1 < NT; ++t) {
        u16* An = As + ((t & 1) ^ 1) * 8192;
        u16* Bn = Bs + ((t & 1) ^ 1) * 8192;
        stageA(An, t + 1); stageB(Bn, t + 1);        // 16 in flight
        asm volatile("s_waitcnt vmcnt(8)" ::: "memory");   // oldest 8 (current tile) done
        SBAR(); SCHED();
        frag_mfma_64_swz(As + (t & 1) * 8192, Bs + (t & 1) * 8192, wm, wn, ln, lh, acc);
        SCHED(); SBAR(); SCHED();
    }
    asm volatile("s_waitcnt vmcnt(0)" ::: "memory");
    SBAR();
    frag_mfma_64_swz(As + ((NT - 1) & 1) * 8192, Bs + ((NT - 1) & 1) * 8192, wm, wn, ln, lh, acc);
    SBAR();
}

// ================= 256^2 8-phase pipeline, deep prefetch (8 waves, 512 thr) =================
// LDS: 2 dbuf x (A[256][64] + B[256][64]) = 128 KiB. Wave (wm = w>>2 in {0,1}, wn = w&3).
// Per K-tile t: 4 phases = C-quadrants. ALL of tile t+2 (A and B) is staged at P3/P4 of
// tile t into buffer cur. vmcnt(8) at P4 completes tile t+1 (issued P3/P4 of t-1:
// 4-5 phase distance ~ HBM latency); never 0 in steady state.

#define T256 16384   // elements per 256x64 tile

// stage 2 of the 4 row-quarter loads of a 256x64 tile (i0, i1 in 0..3; 64 rows each)
DEV void stage2(const u16* __restrict__ gbase, int ld, u16* lds, int tid, int i0, int i1) {
    const int slot = tid & 7;
    {
        const int row = i0 * 64 + (tid >> 3);
        gload16(gbase + (size_t)row * ld + ((slot ^ (row & 7)) << 3),
                lds + ((size_t)(i0 * 512 + (tid & ~63)) << 3));
    }
    {
        const int row = i1 * 64 + (tid >> 3);
        gload16(gbase + (size_t)row * ld + ((slot ^ (row & 7)) << 3),
                lds + ((size_t)(i1 * 512 + (tid & ~63)) << 3));
    }
}

DEV const bf8* frag_ptr(const u16* base, int row, int ks, int lh) {
    const int slot = ((ks << 2) + lh) ^ (row & 7);
    return reinterpret_cast<const bf8*>(base + row * 64 + slot * 8);
}

template<int NT, typename FA, typename FB>
DEV void gemm_pipe8(FA sA, FB sB, u16* As, u16* Bs,
                    int wm, int wn, int ln, int lh, f4 acc[8][4]) {
    // prologue: stage tile0 AND tile1 fully (16 loads); vmcnt(8) -> tile0 resident
    sA(As, 0, 0, 2); sA(As, 0, 1, 3); sB(Bs, 0, 0, 1); sB(Bs, 0, 2, 3);
    if (NT > 1) {
        sA(As + T256, 1, 0, 2); sA(As + T256, 1, 1, 3);
        sB(Bs + T256, 1, 0, 1); sB(Bs + T256, 1, 2, 3);
        asm volatile("s_waitcnt vmcnt(8)" ::: "memory");
    } else {
        asm volatile("s_waitcnt vmcnt(0)" ::: "memory");
    }
    SBAR(); SCHED();
    #pragma unroll 2
    for (int t = 0; t < NT; ++t) {
        const int c = t & 1;
        const u16* Ab = As + c * T256;
        const u16* Bb = Bs + c * T256;
        u16* Ac = As + c * T256;       // stage target for tile t+2 (same parity)
        u16* Bc = Bs + c * T256;
        bf8 aR[8], b0[4], b1[4];
        // ---- P1 (mg0, ng0): read aR(mg0) + b0; no staging ----
        #pragma unroll
        for (int j = 0; j < 4; j++) {
            aR[j]     = *frag_ptr(Ab, wm * 128 + j * 16 + ln, 0, lh);
            aR[4 + j] = *frag_ptr(Ab, wm * 128 + j * 16 + ln, 1, lh);
        }
        #pragma unroll
        for (int k = 0; k < 2; k++) {
            b0[k]     = *frag_ptr(Bb, wn * 64 + k * 16 + ln, 0, lh);
            b0[2 + k] = *frag_ptr(Bb, wn * 64 + k * 16 + ln, 1, lh);
        }
        SBAR(); SCHED();
        __builtin_amdgcn_s_setprio(1);
        #pragma unroll
        for (int j = 0; j < 4; j++) { acc[j][0] = MFMA(aR[j], b0[0], acc[j][0]);
                                      acc[j][1] = MFMA(aR[j], b0[1], acc[j][1]); }
        #pragma unroll
        for (int j = 0; j < 4; j++) { acc[j][0] = MFMA(aR[4 + j], b0[2], acc[j][0]);
                                      acc[j][1] = MFMA(aR[4 + j], b0[3], acc[j][1]); }
        __builtin_amdgcn_s_setprio(0);
        SCHED();
        // ---- P2 (mg0, ng1): read b1; no staging ----
        #pragma unroll
        for (int k = 0; k < 2; k++) {
            b1[k]     = *frag_ptr(Bb, wn * 64 + (2 + k) * 16 + ln, 0, lh);
            b1[2 + k] = *frag_ptr(Bb, wn * 64 + (2 + k) * 16 + ln, 1, lh);
        }
        SBAR(); SCHED();
        __builtin_amdgcn_s_setprio(1);
        #pragma unroll
        for (int j = 0; j < 4; j++) { acc[j][2] = MFMA(aR[j], b1[0], acc[j][2]);
                                      acc[j][3] = MFMA(aR[j], b1[1], acc[j][3]); }
        #pragma unroll
        for (int j = 0; j < 4; j++) { acc[j][2] = MFMA(aR[4 + j], b1[2], acc[j][2]);
                                      acc[j][3] = MFMA(aR[4 + j], b1[3], acc[j][3]); }
        __builtin_amdgcn_s_setprio(0);
        SCHED();
        // ---- P3 (mg1, ng0): read aR(mg1); stage A(t+2){0,2} + B(t+2)h0 ----
        #pragma unroll
        for (int j = 0; j < 4; j++) {
            aR[j]     = *frag_ptr(Ab, wm * 128 + 64 + j * 16 + ln, 0, lh);
            aR[4 + j] = *frag_ptr(Ab, wm * 128 + 64 + j * 16 + ln, 1, lh);
        }
        if (t + 2 < NT) { sA(Ac, t + 2, 0, 2); sB(Bc, t + 2, 0, 1); }
        SBAR(); SCHED();
        __builtin_amdgcn_s_setprio(1);
        #pragma unroll
        for (int j = 0; j < 4; j++) { acc[4 + j][0] = MFMA(aR[j], b0[0], acc[4 + j][0]);
                                      acc[4 + j][1] = MFMA(aR[j], b0[1], acc[4 + j][1]); }
        #pragma unroll
        for (int j = 0; j < 4; j++) { acc[4 + j][0] = MFMA(aR[4 + j], b0[2], acc[4 + j][0]);
                                      acc[4 + j][1] = MFMA(aR[4 + j], b0[3], acc[4 + j][1]); }
        __builtin_amdgcn_s_setprio(0);
        SCHED();
        // ---- P4 (mg1, ng1): stage A(t+2){1,3} + B(t+2)h1; counted vmcnt; no ds_reads ----
        if (t + 2 < NT) {
            sA(Ac, t + 2, 1, 3); sB(Bc, t + 2, 2, 3);
            asm volatile("s_waitcnt vmcnt(8)" ::: "memory");   // tile t+1 resident; t+2 floats
        } else if (t + 1 < NT) {
            asm volatile("s_waitcnt vmcnt(0)" ::: "memory");   // tail drain
        }
        SBAR(); SCHED();
        __builtin_amdgcn_s_setprio(1);
        #pragma unroll
        for (int j = 0; j < 4; j++) { acc[4 + j][2] = MFMA(aR[j], b1[0], acc[4 + j][2]);
                                      acc[4 + j][3] = MFMA(aR[j], b1[1], acc[4 + j][3]); }
        #pragma unroll
        for (int j = 0; j < 4; j++) { acc[4 + j][2] = MFMA(aR[4 + j], b1[2], acc[4 + j][2]);
                                      acc[4 + j][3] = MFMA(aR[4 + j], b1[3], acc[4 + j][3]); }
        __builtin_amdgcn_s_setprio(0);
        SCHED();
    }
}

// ---------------- conversion kernels ----------------
// value [s][b][d] f32 -> xb [b*4096+s][d] bf16
__global__ void k_cvt_x(const float* __restrict__ src, u16* __restrict__ dst) {
    int m = blockIdx.x;                 // m = s*8 + b
    int s = m >> 3, b = m & 7;
    const float* in = src + (size_t)m * 1024;
    u16* outp = dst + (((size_t)b << 12) + s) * 1024;
    int t = threadIdx.x * 4;
    float4 v = *reinterpret_cast<const float4*>(in + t);
    us4 o; o[0] = f2bf(v.x); o[1] = f2bf(v.y); o[2] = f2bf(v.z); o[3] = f2bf(v.w);
    *reinterpret_cast<us4*>(outp + t) = o;
}

// src[R][C] f32 -> dst[C][R] bf16
__global__ void k_transpose(const float* __restrict__ src, u16* __restrict__ dst, int R, int C) {
    __shared__ u16 tile[32][33];
    int tx = threadIdx.x & 31, ty = threadIdx.x >> 5;   // 256 thr: 32x8
    int r0 = blockIdx.y * 32, c0 = blockIdx.x * 32;
    #pragma unroll
    for (int rr = ty; rr < 32; rr += 8)
        tile[rr][tx] = f2bf(src[(size_t)(r0 + rr) * C + c0 + tx]);
    __syncthreads();
    #pragma unroll
    for (int cc = ty; cc < 32; cc += 8)
        dst[(size_t)(c0 + cc) * R + r0 + tx] = tile[tx][cc];
}

// z rows -> klinT[b][s][pos] with affine (gamma3,beta3)
__global__ void k_klinT(const u16* __restrict__ z, const float* __restrict__ gamma,
                        const float* __restrict__ beta, u16* __restrict__ klt) {
    __shared__ u16 tile[32][33];
    int tx = threadIdx.x & 31, ty = threadIdx.x >> 5;
    int r0 = blockIdx.x * 32;            // global row (0..32767)
    int c0 = blockIdx.y * 32;            // s col (0..127)
    float gs = gamma[384 + c0 + tx], bs = beta[384 + c0 + tx];
    #pragma unroll
    for (int rr = ty; rr < 32; rr += 8) {
        u16 zv = z[(size_t)(r0 + rr) * 128 + c0 + tx];
        tile[rr][tx] = f2bf(bf2f(zv) * gs + bs);
    }
    __syncthreads();
    int b = r0 >> 12;
    int pos0 = r0 & 4095;
    #pragma unroll
    for (int cc = ty; cc < 32; cc += 8)
        klt[(((size_t)b * 128 + c0 + cc) << 12) + pos0 + tx] = tile[tx][cc];
}

// ---------------- z/qq/kq/ql = affine(tanh(x @ Wxs + bxs)) (pipelined 128^2) ----------------
__global__ __launch_bounds__(256) void k_zgemm(const u16* __restrict__ xb, const u16* __restrict__ WxsT,
                                               const float* __restrict__ bxs,
                                               const float* __restrict__ gamma, const float* __restrict__ beta,
                                               u16* __restrict__ z, u16* __restrict__ qq,
                                               u16* __restrict__ kq, u16* __restrict__ ql) {
    __shared__ u16 As[2][128 * 64];
    __shared__ u16 Bs[2][128 * 64];
    const int tid = threadIdx.x;
    const int lane = tid & 63, w = tid >> 6;
    const int ln = lane & 15, lh = lane >> 4;
    const int wm = w >> 1, wn = w & 1;
    const int rowbase = xcd_swz(blockIdx.x, 256) * 128;
    const u16* Ab = xb + (size_t)rowbase * 1024;
    f4 acc[4][4] = {};
    gemm_pipe<16>(
        [&](u16* l, int t) { stage128x64(Ab + t * 64, 1024, l, w, lane); },
        [&](u16* l, int t) { stage128x64(WxsT + t * 64, 1024, l, w, lane); },
        As[0], Bs[0], wm, wn, ln, lh, acc);
    #pragma unroll
    for (int mt = 0; mt < 4; mt++)
        #pragma unroll
        for (int nt = 0; nt < 4; nt++) {
            int col = wn * 64 + nt * 16 + ln;
            float bias = bxs[col];
            float g0 = gamma[col],       b0 = beta[col];
            float g1 = gamma[128 + col], b1 = beta[128 + col];
            float g2 = gamma[256 + col], b2 = beta[256 + col];
            int r0 = rowbase + wm * 64 + mt * 16 + lh * 4;
            #pragma unroll
            for (int rg = 0; rg < 4; rg++) {
                float zv = tanhf_fast(acc[mt][nt][rg] + bias);
                size_t idx = ((size_t)(r0 + rg) << 7) + col;
                z[idx]  = f2bf(zv);
                qq[idx] = f2bf(zv * g0 + b0);
                kq[idx] = f2bf(zv * g1 + b1);
                ql[idx] = f2bf(zv * g2 + b2);
            }
        }
}

// ------- vT = tanh(x @ Wve + bve)^T : bf16 [B][2048][4096] (256^2 8-phase, col-major grid) -------
// grid (8, 128): blockIdx.x = col-panel = XCD under round-robin dispatch -> B-panel (0.5 MB)
// stays L2-resident per XCD; A row-panels are co-read by all 8 XCDs -> L3 hits.
__global__ __launch_bounds__(512, 2) void k_vgemm(const u16* __restrict__ xb, const u16* __restrict__ WveT,
                                                  const float* __restrict__ bve, u16* __restrict__ vT) {
    __shared__ u16 As[2 * T256];
    __shared__ u16 Bs[2 * T256];
    const int tid = threadIdx.x;
    const int lane = tid & 63, w = tid >> 6;
    const int ln = lane & 15, lh = lane >> 4;
    const int wm = w >> 2, wn = w & 3;
    const int rowbase = blockIdx.y * 256;
    const int colbase = blockIdx.x * 256;
    const u16* Ag = xb + (size_t)rowbase * 1024;
    const u16* Bg = WveT + (size_t)colbase * 1024;
    f4 acc[8][4] = {};
    gemm_pipe8<16>(
        [&](u16* l, int t, int i0, int i1) { stage2(Ag + t * 64, 1024, l, tid, i0, i1); },
        [&](u16* l, int t, int i0, int i1) { stage2(Bg + t * 64, 1024, l, tid, i0, i1); },
        As, Bs, wm, wn, ln, lh, acc);
    #pragma unroll
    for (int mt = 0; mt < 8; mt++)
        #pragma unroll
        for (int nt = 0; nt < 4; nt++) {
            int e = colbase + wn * 64 + nt * 16 + ln;
            float bias = bve[e];
            int r0 = rowbase + wm * 128 + mt * 16 + lh * 4;
            int bb = r0 >> 12, s0 = r0 & 4095;       // 4 consecutive s, same b
            us4 p;
            #pragma unroll
            for (int rg = 0; rg < 4; rg++) p[rg] = f2bf(tanhf_fast(acc[mt][nt][rg] + bias));
            *reinterpret_cast<us4*>(vT + (((size_t)bb * 2048 + e) << 12) + s0) = p;
        }
}

// ---------------- kvF[b][e][s] += vT[b][e][kseg] @ klinT[b][s][kseg] (pipelined 128^2, K-split x4) --------
__global__ __launch_bounds__(256) void k_kv(const u16* __restrict__ vT, const u16* __restrict__ klt,
                                            float* __restrict__ kvF) {
    __shared__ u16 As[2][128 * 64];
    __shared__ u16 Bs[2][128 * 64];
    const int tid = threadIdx.x;
    const int lane = tid & 63, w = tid >> 6;
    const int ln = lane & 15, lh = lane >> 4;
    const int wm = w >> 1, wn = w & 1;
    const int b = blockIdx.z;
    const int rowbase = blockIdx.x * 128;            // e
    const int kbase = blockIdx.y * 1024;             // pos segment
    const u16* Ab = vT + ((size_t)b * 2048 + rowbase) * 4096 + kbase;
    const u16* Bb = klt + ((size_t)b * 128) * 4096 + kbase;
    f4 acc[4][4] = {};
    gemm_pipe<16>(
        [&](u16* l, int t) { stage128x64(Ab + t * 64, 4096, l, w, lane); },
        [&](u16* l, int t) { stage128x64(Bb + t * 64, 4096, l, w, lane); },
        As[0], Bs[0], wm, wn, ln, lh, acc);
    #pragma unroll
    for (int mt = 0; mt < 4; mt++)
        #pragma unroll
        for (int nt = 0; nt < 4; nt++) {
            int s = wn * 64 + nt * 16 + ln;
            int e0 = rowbase + wm * 64 + mt * 16 + lh * 4;
            #pragma unroll
            for (int rg = 0; rg < 4; rg++)
                atomicAdd(&kvF[(((size_t)b * 2048 + e0 + rg) << 7) + s], acc[mt][nt][rg]);
        }
}

__global__ void k_kvcvt(const float* __restrict__ kvF, u16* __restrict__ kvT, int n) {
    int i = (blockIdx.x * blockDim.x + threadIdx.x) * 4;
    if (i < n) {
        float4 v = *reinterpret_cast<const float4*>(kvF + i);
        us4 o; o[0] = f2bf(v.x); o[1] = f2bf(v.y); o[2] = f2bf(v.z); o[3] = f2bf(v.w);
        *reinterpret_cast<us4*>(kvT + i) = o;
    }
}

// ---------------- a = relu(qq @ kq^T + rel_bias)^2 : bf16 [128][256][256] (pure GEMM) ----------------
__global__ __launch_bounds__(256) void k_a(const u16* __restrict__ qq, const u16* __restrict__ kq,
                                           const float* __restrict__ rel_bias, u16* __restrict__ a_out) {
    const int lane = threadIdx.x & 63, wid = threadIdx.x >> 6;
    const int ln = lane & 15, lh = lane >> 4;
    const int wm = wid >> 1, wn = wid & 1;
    const int ci = blockIdx.y;
    const int qbase = blockIdx.x * 128 + wm * 64;    // q rows within chunk
    const int nbase = wn * 128;                      // key cols within chunk
    const int rowbase = ci << 8;
    f4 acc[4][8] = {};
    const u16* qr[4];
    #pragma unroll
    for (int mt = 0; mt < 4; mt++) qr[mt] = qq + ((size_t)(rowbase + qbase + mt * 16 + ln) << 7);
    const u16* kr[8];
    #pragma unroll
    for (int nt = 0; nt < 8; nt++) kr[nt] = kq + ((size_t)(rowbase + nbase + nt * 16 + ln) << 7);
    #pragma unroll
    for (int kk = 0; kk < 128; kk += 32) {
        int k0 = kk + lh * 8;
        bf8 aq[4], ak[8];
        #pragma unroll
        for (int mt = 0; mt < 4; mt++) aq[mt] = *reinterpret_cast<const bf8*>(qr[mt] + k0);
        #pragma unroll
        for (int nt = 0; nt < 8; nt++) ak[nt] = *reinterpret_cast<const bf8*>(kr[nt] + k0);
        #pragma unroll
        for (int mt = 0; mt < 4; mt++)
            #pragma unroll
            for (int nt = 0; nt < 8; nt++)
                acc[mt][nt] = MFMA(aq[mt], ak[nt], acc[mt][nt]);
    }
    #pragma unroll
    for (int nt = 0; nt < 8; nt++) {
        int key = nbase + nt * 16 + ln;
        float rb = rel_bias[key];
        #pragma unroll
        for (int mt = 0; mt < 4; mt++) {
            int r0 = qbase + mt * 16 + lh * 4;
            #pragma unroll
            for (int rg = 0; rg < 4; rg++) {
                float v = acc[mt][nt][rg] + rb;
                v = fmaxf(v, 0.0f); v = v * v;
                a_out[((size_t)ci << 16) + ((size_t)(r0 + rg) << 8) + key] = f2bf(v);
            }
        }
    }
}

// ---------------- t2 = ql @ kv + a @ v : bf16 [32768][2048] (256^2, 6-tile 8-phase deep) --------
__global__ __launch_bounds__(512, 2) void k_t1(const u16* __restrict__ ql, const u16* __restrict__ a_in,
                                               const u16* __restrict__ vT, const u16* __restrict__ kvT,
                                               u16* __restrict__ t1) {
    __shared__ u16 As[2 * T256];
    __shared__ u16 Bs[2 * T256];
    const int tid = threadIdx.x;
    const int lane = tid & 63, w = tid >> 6;
    const int ln = lane & 15, lh = lane >> 4;
    const int wm = w >> 2, wn = w & 3;
    const int ci = xcd_swz(blockIdx.x, 128);         // chunk == 256-row block
    const int rowbase = ci << 8;
    const int ebase = blockIdx.y * 256;
    const int b = ci >> 4, g = ci & 15;
    const u16* Aa = ql + (size_t)rowbase * 128;                       // tiles 0-1 (ld 128)
    const u16* Ba = kvT + ((size_t)(b * 2048 + ebase)) * 128;         // tiles 0-1 (ld 128)
    const u16* Ab2 = a_in + ((size_t)ci << 16);                       // tiles 2-5 (ld 256)
    const u16* Bb2 = vT + ((size_t)(b * 2048 + ebase)) * 4096 + (g << 8);  // tiles 2-5 (ld 4096)
    f4 acc[8][4] = {};
    gemm_pipe8<6>(
        [&](u16* l, int t, int i0, int i1) {
            if (t < 2) stage2(Aa + t * 64, 128, l, tid, i0, i1);
            else       stage2(Ab2 + (t - 2) * 64, 256, l, tid, i0, i1);
        },
        [&](u16* l, int t, int i0, int i1) {
            if (t < 2) stage2(Ba + t * 64, 128, l, tid, i0, i1);
            else       stage2(Bb2 + (t - 2) * 64, 4096, l, tid, i0, i1);
        },
        As, Bs, wm, wn, ln, lh, acc);
    #pragma unroll
    for (int mt = 0; mt < 8; mt++)
        #pragma unroll
        for (int nt = 0; nt < 4; nt++) {
            int e = ebase + wn * 64 + nt * 16 + ln;
            int r0 = rowbase + wm * 128 + mt * 16 + lh * 4;
            #pragma unroll
            for (int rg = 0; rg < 4; rg++)
                t1[((size_t)(r0 + rg) << 11) + e] = f2bf(acc[mt][nt][rg]);
        }
}

// ------- t1 = tanh(x @ Wue + bue) * t2 (in place, 256^2 8-phase, col-major grid) -------
__global__ __launch_bounds__(512, 2) void k_u(const u16* __restrict__ xb, const u16* __restrict__ WueT,
                                              const float* __restrict__ bue, u16* t1) {
    __shared__ u16 As[2 * T256];
    __shared__ u16 Bs[2 * T256];
    const int tid = threadIdx.x;
    const int lane = tid & 63, w = tid >> 6;
    const int ln = lane & 15, lh = lane >> 4;
    const int wm = w >> 2, wn = w & 3;
    const int rowbase = blockIdx.y * 256;
    const int colbase = blockIdx.x * 256;
    const u16* Ag = xb + (size_t)rowbase * 1024;
    const u16* Bg = WueT + (size_t)colbase * 1024;
    f4 acc[8][4] = {};
    gemm_pipe8<16>(
        [&](u16* l, int t, int i0, int i1) { stage2(Ag + t * 64, 1024, l, tid, i0, i1); },
        [&](u16* l, int t, int i0, int i1) { stage2(Bg + t * 64, 1024, l, tid, i0, i1); },
        As, Bs, wm, wn, ln, lh, acc);
    #pragma unroll
    for (int mt = 0; mt < 8; mt++)
        #pragma unroll
        for (int nt = 0; nt < 4; nt++) {
            int e = colbase + wn * 64 + nt * 16 + ln;
            float bias = bue[e];
            int r0 = rowbase + wm * 128 + mt * 16 + lh * 4;
            #pragma unroll
            for (int rg = 0; rg < 4; rg++) {
                size_t idx = ((size_t)(r0 + rg) << 11) + e;
                float t = bf2f(t1[idx]);
                float u = tanhf_fast(acc[mt][nt][rg] + bias);
                t1[idx] = f2bf(u * t);
            }
        }
}

// ------- out = t1 @ Wod + bod -> [s][b][d] f32 (256^2 8-phase, col-major grid) -------
__global__ __launch_bounds__(512, 2) void k_o(const u16* __restrict__ t1, const u16* __restrict__ WodT,
                                              const float* __restrict__ bod, float* __restrict__ out) {
    __shared__ u16 As[2 * T256];
    __shared__ u16 Bs[2 * T256];
    const int tid = threadIdx.x;
    const int lane = tid & 63, w = tid >> 6;
    const int ln = lane & 15, lh = lane >> 4;
    const int wm = w >> 2, wn = w & 3;
    const int rowbase = blockIdx.y * 256;
    const int colbase = blockIdx.x * 256;
    const u16* Ag = t1 + (size_t)rowbase * 2048;
    const u16* Bg = WodT + (size_t)colbase * 2048;
    f4 acc[8][4] = {};
    gemm_pipe8<32>(
        [&](u16* l, int t, int i0, int i1) { stage2(Ag + t * 64, 2048, l, tid, i0, i1); },
        [&](u16* l, int t, int i0, int i1) { stage2(Bg + t * 64, 2048, l, tid, i0, i1); },
        As, Bs, wm, wn, ln, lh, acc);
    #pragma unroll
    for (int mt = 0; mt < 8; mt++)
        #pragma unroll
        for (int nt = 0; nt < 4; nt++) {
            int d = colbase + wn * 64 + nt * 16 + ln;
            float bias = bod[d];
            int r0 = rowbase + wm * 128 + mt * 16 + lh * 4;
            #pragma unroll
            for (int rg = 0; rg < 4; rg++) {
                int r = r0 + rg;
                int s = r & 4095, bb = r >> 12;
                out[((size_t)(s * 8 + bb) << 10) + d] = acc[mt][nt][rg] + bias;
            }
        }
}

extern "C" void kernel_launch(void* const* d_in, const int* in_sizes, int n_in,
                              void* d_out, int out_size, void* d_ws, size_t ws_size,
                              hipStream_t stream) {
    const float* value = (const float*)d_in[2];
    const float* Wxs = (const float*)d_in[3];  const float* bxs = (const float*)d_in[4];
    const float* Wve = (const float*)d_in[5];  const float* bve = (const float*)d_in[6];
    const float* Wue = (const float*)d_in[7];  const float* bue = (const float*)d_in[8];
    const float* Wod = (const float*)d_in[9];  const float* bod = (const float*)d_in[10];
    const float* rel_bias = (const float*)d_in[11];
    const float* gamma = (const float*)d_in[12];
    const float* beta  = (const float*)d_in[13];
    float* out = (float*)d_out;

    char* ws = (char*)d_ws;
    u16* xb   = (u16*)(ws + WS_XB);
    u16* WxsT = (u16*)(ws + WS_WXST);
    u16* WveT = (u16*)(ws + WS_WVET);
    u16* WueT = (u16*)(ws + WS_WUET);
    u16* WodT = (u16*)(ws + WS_WODT);
    u16* kvT  = (u16*)(ws + WS_KVT);
    u16* a    = (u16*)(ws + WS_A);
    u16* ql   = (u16*)(ws + WS_QL);
    u16* vT   = (u16*)(ws + WS_VT);
    u16* t1   = (u16*)(ws + WS_T1);
    u16* z    = (u16*)(ws + WS_Z);
    u16* klt  = (u16*)(ws + WS_KLT);
    u16* qq   = (u16*)(ws + WS_QQ);
    u16* kq   = (u16*)(ws + WS_KQ);
    float* kvF = (float*)(ws + WS_KVF);

    // conversions
    k_cvt_x<<<32768, 256, 0, stream>>>(value, xb);
    k_transpose<<<dim3(4, 32),  256, 0, stream>>>(Wxs, WxsT, 1024, 128);
    k_transpose<<<dim3(64, 32), 256, 0, stream>>>(Wve, WveT, 1024, 2048);
    k_transpose<<<dim3(64, 32), 256, 0, stream>>>(Wue, WueT, 1024, 2048);
    k_transpose<<<dim3(32, 64), 256, 0, stream>>>(Wod, WodT, 2048, 1024);
    // z + affine variants (pipelined 128^2)
    k_zgemm<<<256, 256, 0, stream>>>(xb, WxsT, bxs, gamma, beta, z, qq, kq, ql);
    // k_lin transposed
    k_klinT<<<dim3(1024, 4), 256, 0, stream>>>(z, gamma, beta, klt);
    // v (256^2 8-phase deep, col-major grid: x = col-panel = XCD)
    k_vgemm<<<dim3(8, 128), 512, 0, stream>>>(xb, WveT, bve, vT);
    // kv (pipelined 128^2, K-split x4 atomics)
    hipMemsetAsync(kvF, 0, (size_t)8 * 2048 * 128 * 4, stream);
    k_kv<<<dim3(16, 4, 8), 256, 0, stream>>>(vT, klt, kvF);
    k_kvcvt<<<2048, 256, 0, stream>>>(kvF, kvT, 8 * 2048 * 128);
    // quadratic attention scores (pure GEMM)
    k_a<<<dim3(2, 128), 256, 0, stream>>>(qq, kq, rel_bias, a);
    // t2 = v_quad + v_lin (256^2, 6 tiles, 8-phase deep)
    k_t1<<<dim3(128, 8), 512, 0, stream>>>(ql, a, vT, kvT, t1);
    // t1 = tanh(u) * t2 (256^2 8-phase deep, col-major grid, in place)
    k_u<<<dim3(8, 128), 512, 0, stream>>>(xb, WueT, bue, t1);
    // out (256^2 8-phase deep, col-major grid)
    k_o<<<dim3(4, 128), 512, 0, stream>>>(t1, WodT, bod, out);
}